// Round 11
// baseline (9964.406 us; speedup 1.0000x reference)
//
#include <hip/hip_runtime.h>
#include <hip/hip_bf16.h>

typedef __bf16 bf16x8 __attribute__((ext_vector_type(8)));
typedef float  f32x4  __attribute__((ext_vector_type(4)));
typedef float  f32x8  __attribute__((ext_vector_type(8)));
typedef int    i32x4  __attribute__((ext_vector_type(4)));

#define T_LEN 1024
#define DD    512
#define HH    512
#define NBLK  64     // 64 consumer blocks x 8 h-cols = 512 = H (+64 producers)
#define DEPTH 8      // xW ring depth; 64*8*4KB = 2 MB in d_ws
#define HSLOTS 4     // h-ring slots (max block skew is 1; 4 = margin)
#define FSTRIDE 8    // progress-word spacing: 8 uints = 32 B

__device__ __forceinline__ f32x4 mfma16(bf16x8 a, bf16x8 b, f32x4 c) {
    return __builtin_amdgcn_mfma_f32_16x16x32_bf16(a, b, c, 0, 0, 0);
}
__device__ __forceinline__ float sigmf_(float v) { return 1.f / (1.f + __expf(-v)); }
__device__ __forceinline__ float tanhf_(float v) { return 1.f - 2.f / (1.f + __expf(2.f * v)); }
__device__ __forceinline__ bf16x8 cvt8(f32x8 v) {
    bf16x8 r;
    #pragma unroll
    for (int j = 0; j < 8; ++j) r[j] = (__bf16)v[j];
    return r;
}

// 16 sc1 16-B loads at byte offsets kk*128 from base (issue only, no wait).
__device__ __forceinline__ void issue16(const unsigned* b, i32x4 f[16]) {
    asm volatile(
        "global_load_dwordx4 %0, %16, off sc1\n\t"
        "global_load_dwordx4 %1, %16, off offset:128 sc1\n\t"
        "global_load_dwordx4 %2, %16, off offset:256 sc1\n\t"
        "global_load_dwordx4 %3, %16, off offset:384 sc1\n\t"
        "global_load_dwordx4 %4, %16, off offset:512 sc1\n\t"
        "global_load_dwordx4 %5, %16, off offset:640 sc1\n\t"
        "global_load_dwordx4 %6, %16, off offset:768 sc1\n\t"
        "global_load_dwordx4 %7, %16, off offset:896 sc1\n\t"
        "global_load_dwordx4 %8, %16, off offset:1024 sc1\n\t"
        "global_load_dwordx4 %9, %16, off offset:1152 sc1\n\t"
        "global_load_dwordx4 %10, %16, off offset:1280 sc1\n\t"
        "global_load_dwordx4 %11, %16, off offset:1408 sc1\n\t"
        "global_load_dwordx4 %12, %16, off offset:1536 sc1\n\t"
        "global_load_dwordx4 %13, %16, off offset:1664 sc1\n\t"
        "global_load_dwordx4 %14, %16, off offset:1792 sc1\n\t"
        "global_load_dwordx4 %15, %16, off offset:1920 sc1"
        : "=&v"(f[0]), "=&v"(f[1]), "=&v"(f[2]), "=&v"(f[3]),
          "=&v"(f[4]), "=&v"(f[5]), "=&v"(f[6]), "=&v"(f[7]),
          "=&v"(f[8]), "=&v"(f[9]), "=&v"(f[10]), "=&v"(f[11]),
          "=&v"(f[12]), "=&v"(f[13]), "=&v"(f[14]), "=&v"(f[15])
        : "v"(b)
        : "memory");
}

// single sc1 16-B load (issue only)
__device__ __forceinline__ void issue1(const float* p, i32x4* rv) {
    asm volatile("global_load_dwordx4 %0, %1, off sc1"
                 : "=&v"(*rv) : "v"(p) : "memory");
}

// wait for all issued loads; fence against MFMA hoisting (rule #18)
__device__ __forceinline__ void wait_all() {
    asm volatile("s_waitcnt vmcnt(0)" ::: "memory");
    __builtin_amdgcn_sched_barrier(0);
}

// ring-only poll (t==0: h comes from h0 input, only xW needs the ring)
__device__ __forceinline__ i32x4 poll_ring(const float* rp) {
    i32x4 rv;
    for (;;) {
        asm volatile(
            "global_load_dwordx4 %0, %1, off sc1\n\t"
            "s_waitcnt vmcnt(0)"
            : "=&v"(rv) : "v"(rp) : "memory");
        if (__all((rv[0] != 0) & (rv[2] != 0))) break;
        __builtin_amdgcn_s_sleep(1);
    }
    return rv;
}

// build bf16x8 from the hi-16 of 8 epoch-carrying u32s
__device__ __forceinline__ bf16x8 unpack_hi(i32x4 a, i32x4 b) {
    i32x4 r;
    r[0] = (int)(((unsigned)a[1] & 0xFFFF0000u) | ((unsigned)a[0] >> 16));
    r[1] = (int)(((unsigned)a[3] & 0xFFFF0000u) | ((unsigned)a[2] >> 16));
    r[2] = (int)(((unsigned)b[1] & 0xFFFF0000u) | ((unsigned)b[0] >> 16));
    r[3] = (int)(((unsigned)b[3] & 0xFFFF0000u) | ((unsigned)b[2] >> 16));
    return *(bf16x8*)&r;
}

__device__ __forceinline__ void xpart_mfma(const float* xr, const bf16x8* wbh, const bf16x8* wbl,
                                           f32x4& ac0, f32x4& ac1, f32x4& ac2, f32x4& ac3) {
    #pragma unroll
    for (int kk = 0; kk < 16; ++kk) {
        bf16x8 av = cvt8(*(const f32x8*)(xr + kk * 32));
        if (kk & 1) { ac1 = mfma16(av, wbh[kk], ac1); ac3 = mfma16(av, wbl[kk], ac3); }
        else        { ac0 = mfma16(av, wbh[kk], ac0); ac2 = mfma16(av, wbl[kk], ac2); }
    }
}

// Round 17 = round 14 (producer/consumer, verified 5249 us) + compact
// epoch-carrying h-ring: h exchanged through a dedicated 256 KB ring in d_ws
// (4 slots x 32x512 u32 = bf16(h)<<16 | epoch(t+1)) instead of bf16 stashes
// scattered at 2 MB stride inside `out`. Epoch-in-data removes the zero
// sentinel, re-zero stores, ws16 arena and the t==T-1 special case; each 8-B
// atomic pair self-validates. Slot reuse at distance 4 is unreachable (block
// skew <= 1 step), so the h-ring needs NO protocol. xW ring + progress: r14.
__global__ void __launch_bounds__(256, 1)
lstm_pk(const float* __restrict__ x,    // (32,1024,512) fp32
        const float* __restrict__ h0,   // (32,512)
        const float* __restrict__ Wx,   // (512,2048)
        const float* __restrict__ Wh,   // (512,2048)
        const float* __restrict__ bias, // (2048)
        float* __restrict__ out,        // (32,1024,512) fp32
        unsigned* __restrict__ hring,   // HSLOTS*32*512 u32 (zeroed)
        unsigned* __restrict__ progress,// 64 words, 32-B spaced (zeroed)
        float* __restrict__ ring)       // 64*DEPTH*1024 f32 (zeroed)
{
    __shared__ float a_lds[32][36];

    const int tid  = threadIdx.x;
    const bool isprod = (blockIdx.x >= NBLK);
    const int blk  = isprod ? (blockIdx.x - NBLK) : blockIdx.x;
    const int hc0  = blk * 8;
    const int lane = tid & 63;
    const int wid  = tid >> 6;          // 4 waves: wid&1 = m-tile, wid>>1 = n-tile
    const int q    = lane >> 4;
    const int mrow = (wid & 1) * 16 + (lane & 15);
    const int bcol = (wid >> 1) * 16 + (lane & 15);
    const int gcol = (bcol >> 3) * HH + hc0 + (bcol & 7);

    // ---- one-time: role-specific weight B-frags, bf16 hi+lo split ----
    const float* wsrc = isprod ? Wx : Wh;
    bf16x8 wbh[16], wbl[16];
    #pragma unroll
    for (int kk = 0; kk < 16; ++kk) {
        const int kb = kk * 32 + q * 8;
        bf16x8 wh_, wl_;
        #pragma unroll
        for (int j = 0; j < 8; ++j) {
            float w = wsrc[(size_t)(kb + j) * (4 * HH) + gcol];
            __bf16 hi = (__bf16)w;
            wh_[j] = hi;
            wl_[j] = (__bf16)(w - (float)hi);
        }
        wbh[kk] = wh_; wbl[kk] = wl_;
    }

    float* rbase = ring + (size_t)blk * DEPTH * 1024;

    // ================= producer role (r14 verbatim) =================
    if (isprod) {
        const float* xrow0 = x + (size_t)mrow * T_LEN * DD + q * 8;
        unsigned last = 0;
        #pragma unroll 1
        for (int t = 0; t < T_LEN; ++t) {
            while (t >= (int)last + DEPTH) {
                last = __hip_atomic_load(progress + blk * FSTRIDE,
                                         __ATOMIC_RELAXED, __HIP_MEMORY_SCOPE_AGENT);
                if (t >= (int)last + DEPTH) __builtin_amdgcn_s_sleep(8);
            }
            f32x4 a0 = {0,0,0,0}, a1 = {0,0,0,0}, a2 = {0,0,0,0}, a3 = {0,0,0,0};
            xpart_mfma(xrow0 + (size_t)t * DD, wbh, wbl, a0, a1, a2, a3);
            f32x4 s = (a0 + a1) + (a2 + a3);
            unsigned u0 = __float_as_uint(s[0]); if (!u0) u0 = 1u;
            unsigned u1 = __float_as_uint(s[1]); if (!u1) u1 = 1u;
            unsigned u2 = __float_as_uint(s[2]); if (!u2) u2 = 1u;
            unsigned u3 = __float_as_uint(s[3]); if (!u3) u3 = 1u;
            unsigned long long lo = ((unsigned long long)u1 << 32) | u0;
            unsigned long long hi = ((unsigned long long)u3 << 32) | u2;
            unsigned long long* dst =
                (unsigned long long*)(rbase + (size_t)(t & (DEPTH - 1)) * 1024 + tid * 4);
            __hip_atomic_store(dst,     lo, __ATOMIC_RELAXED, __HIP_MEMORY_SCOPE_AGENT);
            __hip_atomic_store(dst + 1, hi, __ATOMIC_RELAXED, __HIP_MEMORY_SCOPE_AGENT);
        }
        return;
    }

    // ================= consumer role =================
    const int gn  = tid >> 3;
    const int glc = tid & 7;
    const float bi  = bias[0 * HH + hc0 + glc];
    const float bf_ = bias[1 * HH + hc0 + glc];
    const float bo  = bias[2 * HH + hc0 + glc];
    const float bg  = bias[3 * HH + hc0 + glc];
    float creg = 0.f;
    const size_t outoff = (size_t)gn * T_LEN * HH + hc0 + glc;

    // h-ring addressing: reader base for (mrow, k = kk*32 + q*8 + j)
    const unsigned* hrd = hring + (size_t)mrow * HH + q * 8;   // + slot*16384
    unsigned* hwr = hring + (size_t)gn * HH + hc0 + glc;       // + slot*16384

    #pragma unroll 1
    for (int t = 0; t < T_LEN; ++t) {
        const float* rp = rbase + (size_t)(t & (DEPTH - 1)) * 1024 + tid * 4;
        bf16x8 hfrag[16];
        i32x4 rv;
        if (t == 0) {
            #pragma unroll
            for (int kk = 0; kk < 16; ++kk)
                hfrag[kk] = cvt8(*(const f32x8*)(h0 + (size_t)mrow * HH + kk * 32 + q * 8));
            rv = poll_ring(rp);
        } else {
            // poll h(t-1): slot (t-1)&3, epoch == t (never 0; initial zeros fail)
            const unsigned* ha = hrd + (size_t)((t - 1) & (HSLOTS - 1)) * 16384;
            const unsigned* hb = ha + 4;         // +16 B: cols +4..+7 of each frag
            const unsigned ep = (unsigned)t;
            i32x4 fa[16], fb[16];
            for (;;) {
                issue16(ha, fa);
                issue16(hb, fb);
                issue1(rp, &rv);
                wait_all();
                unsigned ok = 1u;
                #pragma unroll
                for (int kk = 0; kk < 16; ++kk) {
                    ok &= ((unsigned)fa[kk][0] & 0xFFFFu) == ep;   // 8-B unit 1
                    ok &= ((unsigned)fa[kk][2] & 0xFFFFu) == ep;   // 8-B unit 2
                    ok &= ((unsigned)fb[kk][0] & 0xFFFFu) == ep;   // 8-B unit 3
                    ok &= ((unsigned)fb[kk][2] & 0xFFFFu) == ep;   // 8-B unit 4
                }
                ok &= (unsigned)((rv[0] != 0) & (rv[2] != 0));
                if (__all((int)ok)) break;
                __builtin_amdgcn_s_sleep(1);
            }
            #pragma unroll
            for (int kk = 0; kk < 16; ++kk) hfrag[kk] = unpack_hi(fa[kk], fb[kk]);
        }

        // ---- h-part MFMAs (x-part arrives via xW ring) ----
        f32x4 ac0 = {0,0,0,0}, ac1 = {0,0,0,0}, ac2 = {0,0,0,0}, ac3 = {0,0,0,0};
        #pragma unroll
        for (int kk = 0; kk < 16; ++kk) {
            if (kk & 1) { ac1 = mfma16(hfrag[kk], wbh[kk], ac1); ac3 = mfma16(hfrag[kk], wbl[kk], ac3); }
            else        { ac0 = mfma16(hfrag[kk], wbh[kk], ac0); ac2 = mfma16(hfrag[kk], wbl[kk], ac2); }
        }
        f32x4 av4 = (ac0 + ac1) + (ac2 + ac3);
        av4[0] += __uint_as_float(rv[0]);
        av4[1] += __uint_as_float(rv[1]);
        av4[2] += __uint_as_float(rv[2]);
        av4[3] += __uint_as_float(rv[3]);

        // ---- re-zero consumed xW slot (epoch scheme covers only the h-ring;
        // xW ring keeps r14's zero-sentinel protocol) ----
        {
            unsigned long long* zp = (unsigned long long*)rp;
            __hip_atomic_store(zp,     0ull, __ATOMIC_RELAXED, __HIP_MEMORY_SCOPE_AGENT);
            __hip_atomic_store(zp + 1, 0ull, __ATOMIC_RELAXED, __HIP_MEMORY_SCOPE_AGENT);
        }

        __syncthreads();                 // (1) gates(t-1) done; re-zeros drained
        if (tid == 0)                    // (per-wave vmcnt(0) in __syncthreads)
            __hip_atomic_store(progress + blk * FSTRIDE, (unsigned)t,
                               __ATOMIC_RELAXED, __HIP_MEMORY_SCOPE_AGENT);
        #pragma unroll
        for (int r = 0; r < 4; ++r)
            a_lds[(wid & 1) * 16 + q * 4 + r][bcol] = av4[r];
        __syncthreads();                 // (2) a_lds(t) published

        // ---- gates ----
        float ai = a_lds[gn][glc]      + bi;
        float af = a_lds[gn][8 + glc]  + bf_;
        float ao = a_lds[gn][16 + glc] + bo;
        float ag = a_lds[gn][24 + glc] + bg;
        float iv = sigmf_(ai), fv = sigmf_(af), ov = sigmf_(ao);
        float gv = tanhf_(ag);
        creg = fv * creg + iv * gv;
        float hv = ov * tanhf_(creg);

        // ---- pack (intra-wave shuffles; glc = tid&7 so partners same wave) ----
        unsigned hvu = __float_as_uint(hv);
        unsigned long long opair =
            ((unsigned long long)__shfl_xor(hvu, 1) << 32) | (unsigned long long)hvu;
        __bf16 hb16 = (__bf16)hv;
        unsigned hw32 = ((unsigned)*(unsigned short*)&hb16 << 16) | ((unsigned)(t + 1) & 0xFFFFu);
        unsigned long long hpair =
            ((unsigned long long)__shfl_xor(hw32, 1) << 32) | (unsigned long long)hw32;

        // ---- fire-and-forget stores ----
        if ((glc & 1) == 0) {
            __hip_atomic_store((unsigned long long*)(out + outoff + (size_t)t * HH),
                               opair, __ATOMIC_RELAXED, __HIP_MEMORY_SCOPE_AGENT);
            if (t < T_LEN - 1)           // publish h(t) with epoch t+1
                __hip_atomic_store((unsigned long long*)(hwr + (size_t)(t & (HSLOTS - 1)) * 16384),
                                   hpair, __ATOMIC_RELAXED, __HIP_MEMORY_SCOPE_AGENT);
        }
    }
}

extern "C" void kernel_launch(void* const* d_in, const int* in_sizes, int n_in,
                              void* d_out, int out_size, void* d_ws, size_t ws_size,
                              hipStream_t stream) {
    const float* x  = (const float*)d_in[0];
    const float* h0 = (const float*)d_in[1];
    const float* Wx = (const float*)d_in[2];
    const float* Wh = (const float*)d_in[3];
    const float* b  = (const float*)d_in[4];
    float* out = (float*)d_out;
    // d_ws layout: [0,4K) progress | [4K, 4K+256K) h-ring | [+, +2M) xW ring
    unsigned* progress = (unsigned*)d_ws;
    unsigned* hring    = (unsigned*)((char*)d_ws + 4096);
    float* ring        = (float*)((char*)d_ws + 4096 + (size_t)HSLOTS * 32 * HH * 4);
    const size_t init_bytes = 4096 + (size_t)HSLOTS * 32 * HH * 4
                            + (size_t)NBLK * DEPTH * 1024 * sizeof(float);

    // Zero-init: progress, h-ring epochs, xW ring sentinels.
    hipMemsetAsync(d_ws, 0, init_bytes, stream);
    lstm_pk<<<dim3(2 * NBLK), dim3(256), 0, stream>>>(x, h0, Wx, Wh, b, out,
                                                      hring, progress, ring);
}